// Round 10
// baseline (239.155 us; speedup 1.0000x reference)
//
#include <hip/hip_runtime.h>
#include <hip/hip_bf16.h>
#include <math.h>

#define B 64
#define O 64
#define F 1024
#define RN 16
#define RD 256
#define DEPTH 2
#define M (B*O)

typedef __attribute__((ext_vector_type(8))) _Float16 half8;
typedef __attribute__((ext_vector_type(4))) float f32x4;

#define RES_SCALE 2048.0f          // 2^11
#define RES_INV  (1.0f/2048.0f)

// ---------- fp16 split helpers: x = h + l*2^-11 (l stored pre-scaled) ----------
__device__ __forceinline__ unsigned short h2u(_Float16 h) {
  union { _Float16 h; unsigned short u; } c; c.h = h; return c.u;
}
__device__ __forceinline__ void split2(float x, unsigned short& h, unsigned short& l) {
  _Float16 hh = (_Float16)x;                       // RNE
  _Float16 ll = (_Float16)((x - (float)hh) * RES_SCALE);
  h = h2u(hh); l = h2u(ll);
}

__device__ __forceinline__ void gload_lds16(const unsigned short* g, void* l) {
  __builtin_amdgcn_global_load_lds(
      (const __attribute__((address_space(1))) unsigned int*)g,
      (__attribute__((address_space(3))) unsigned int*)l, 16, 0, 0);
}

// ---------------- A reductions: A1[b,o,o2] = sum_r A, A2[b,o,r] = sum_o2 A ----
__global__ __launch_bounds__(256) void k_reduceA(const float* __restrict__ A,
                                                 float* __restrict__ A1,
                                                 float* __restrict__ A2) {
  __shared__ float row[O * RN];
  const int bo = blockIdx.x;
  const int t = threadIdx.x;
  *reinterpret_cast<float4*>(&row[t * 4]) =
      *reinterpret_cast<const float4*>(&A[(size_t)bo * (O * RN) + t * 4]);
  __syncthreads();
  if (t < O) {
    float s = 0.f;
#pragma unroll
    for (int r = 0; r < RN; ++r) s += row[t * RN + r];
    A1[(size_t)bo * O + t] = s;
  } else if (t < O + RN) {
    const int r = t - O;
    float s = 0.f;
#pragma unroll
    for (int o2 = 0; o2 < O; ++o2) s += row[o2 * RN + r];
    A2[(size_t)bo * RN + r] = s;
  }
}

// ------- xr_r = R @ Wrel[i][F:] + brel[i] -> xrr[layer][RN][F], both layers ---
__global__ __launch_bounds__(256) void k_xrr(const float* __restrict__ R,
                                             const float* __restrict__ Wrel,
                                             const float* __restrict__ brel,
                                             float* __restrict__ xrr) {
  const int layer = blockIdx.y;
  const float* Wr = Wrel + (size_t)layer * (F + RD) * F + (size_t)F * F;
  const float* br = brel + (size_t)layer * F;
  const int r = blockIdx.x >> 2;
  const int n = ((blockIdx.x & 3) << 8) + threadIdx.x;
  float s = br[n];
  for (int k = 0; k < RD; ++k) s += R[r * RD + k] * Wr[(size_t)k * F + n];
  xrr[(size_t)layer * RN * F + (size_t)r * F + n] = s;
}

// ---------------- split X [4096][1024] f32 -> Xh, Xl fp16 (row-major) --------
__global__ __launch_bounds__(256) void k_splitX(const float* __restrict__ X,
                                                unsigned short* __restrict__ Xh,
                                                unsigned short* __restrict__ Xl) {
  const size_t i = ((size_t)blockIdx.x * 256 + threadIdx.x) * 4;
  const float4 v = *reinterpret_cast<const float4*>(&X[i]);
  unsigned short h0, h1, h2, h3, l0, l1, l2, l3;
  split2(v.x, h0, l0); split2(v.y, h1, l1); split2(v.z, h2, l2); split2(v.w, h3, l3);
  uint2 hp, lp;
  hp.x = (unsigned)h0 | ((unsigned)h1 << 16); hp.y = (unsigned)h2 | ((unsigned)h3 << 16);
  lp.x = (unsigned)l0 | ((unsigned)l1 << 16); lp.y = (unsigned)l2 | ((unsigned)l3 << 16);
  *reinterpret_cast<uint2*>(&Xh[i]) = hp;
  *reinterpret_cast<uint2*>(&Xl[i]) = lp;
}

// -- split + transpose W for BOTH layers upfront.
// z = layer*2 + sel; sel 0: Wself -> rows [0,1024); sel 1: Wrel[:F] -> rows [1024,2048).
__global__ __launch_bounds__(256) void k_splitW2(const float* __restrict__ Wself,
                                                 const float* __restrict__ Wrel,
                                                 unsigned short* __restrict__ Wht,
                                                 unsigned short* __restrict__ Wlt) {
  __shared__ float T[32][33];
  const int layer = blockIdx.z >> 1;
  const int sel = blockIdx.z & 1;
  const float* W = sel ? (Wrel + (size_t)layer * (F + RD) * F)
                       : (Wself + (size_t)layer * F * F);
  const size_t obase = (size_t)layer * 2048 * 1024 + (size_t)(sel ? 1024 : 0) * 1024;
  const int k0 = blockIdx.x * 32, n0 = blockIdx.y * 32;
  const int t = threadIdx.x;
  const int r = t >> 3, c4 = (t & 7) << 2;
  const float4 v = *reinterpret_cast<const float4*>(&W[(size_t)(k0 + r) * 1024 + n0 + c4]);
  T[r][c4] = v.x; T[r][c4 + 1] = v.y; T[r][c4 + 2] = v.z; T[r][c4 + 3] = v.w;
  __syncthreads();
  unsigned short h[4], l[4];
#pragma unroll
  for (int j = 0; j < 4; ++j) split2(T[c4 + j][r], h[j], l[j]);
  uint2 hp, lp;
  hp.x = (unsigned)h[0] | ((unsigned)h[1] << 16); hp.y = (unsigned)h[2] | ((unsigned)h[3] << 16);
  lp.x = (unsigned)l[0] | ((unsigned)l[1] << 16); lp.y = (unsigned)l[2] | ((unsigned)l[3] << 16);
  const size_t o = obase + (size_t)(n0 + r) * 1024 + k0 + c4;
  *reinterpret_cast<uint2*>(&Wht[o]) = hp;
  *reinterpret_cast<uint2*>(&Wlt[o]) = lp;
}

// ---------------- staging + compute helpers for the MFMA GEMM ----------------
__device__ __forceinline__ void stage_tiles(const unsigned short* __restrict__ Asrc,
                                            const unsigned short* __restrict__ Bsrc,
                                            int bm, int bn, int k0,
                                            int w, int srow, int sin,
                                            char* Al, char* Bl) {
#pragma unroll
  for (int i = 0; i < 4; ++i) {
    const int c = (w << 2) + i;          // chunk 0..15, wave-uniform
    const int row = (c << 3) + srow;
    const int inrow = sin ^ ((row & 7) << 4);   // pre-swizzled SOURCE byte
    gload_lds16(Asrc + ((size_t)(bm + row) << 10) + k0 + (inrow >> 1), Al + (c << 10));
    gload_lds16(Bsrc + ((size_t)(bn + row) << 10) + k0 + (inrow >> 1), Bl + (c << 10));
  }
}

__device__ __forceinline__ void compute_tile(const char* Al, const char* Bl,
                                             int ar, int br, int kbyte,
                                             f32x4 (&acc)[4][4]) {
#pragma unroll
  for (int kk = 0; kk < 2; ++kk) {
    half8 a[4], b[4];
#pragma unroll
    for (int m = 0; m < 4; ++m) {
      const int row = ar + m * 16;
      const int off = (row << 7) + (((kk << 6) + kbyte) ^ ((row & 7) << 4));
      a[m] = *reinterpret_cast<const half8*>(&Al[off]);
    }
#pragma unroll
    for (int n = 0; n < 4; ++n) {
      const int row = br + n * 16;
      const int off = (row << 7) + (((kk << 6) + kbyte) ^ ((row & 7) << 4));
      b[n] = *reinterpret_cast<const half8*>(&Bl[off]);
    }
#pragma unroll
    for (int m = 0; m < 4; ++m)
#pragma unroll
      for (int n = 0; n < 4; ++n)
        acc[m][n] = __builtin_amdgcn_mfma_f32_16x16x32_f16(a[m], b[n], acc[m][n], 0, 0, 0);
  }
}

// One pipelined K-step: prefetch next tile into buf^1 (stays in flight across
// the barrier — counted vmcnt(8), never 0 mid-loop), then compute current buf.
// Two barriers: entry barrier gates buf[par] data; exit barrier protects
// buf[par] against next step's overwrite (WAR).
__device__ __forceinline__ void pipe_step(bool hn,
                                          const unsigned short* An,
                                          const unsigned short* Bn, int k0n,
                                          int par,
                                          int bm, int bn, int w, int srow, int sin,
                                          int ar, int br, int kbyte,
                                          char (*LA)[16384], char (*LB)[16384],
                                          f32x4 (&acc)[4][4]) {
  if (hn) {
    stage_tiles(An, Bn, bm, bn, k0n << 6, w, srow, sin, LA[par ^ 1], LB[par ^ 1]);
    asm volatile("s_waitcnt vmcnt(8)" ::: "memory");   // wait prev stage only
  } else {
    asm volatile("s_waitcnt vmcnt(0)" ::: "memory");   // last step: drain
  }
  __builtin_amdgcn_s_barrier();
  __builtin_amdgcn_sched_barrier(0);
  compute_tile(LA[par], LB[par], ar, br, kbyte, acc);
  __builtin_amdgcn_s_barrier();
}

// ------- fused MFMA GEMM (R6 organization + dbuf counted-vmcnt pipeline) ------
// xrx half (bn>=1024): C = Xh@Wh + 2^-11*(Xh@Wl_st + Xl_st@Wh), K=3072 always.
// xs  half (bn< 1024): same if xs_full, else single product Xh@Wh (K=1024).
__global__ __launch_bounds__(256) void k_gemm_mfma(
    const unsigned short* __restrict__ Xh, const unsigned short* __restrict__ Xl,
    const unsigned short* __restrict__ Wht, const unsigned short* __restrict__ Wlt,
    float* __restrict__ xs, float* __restrict__ xrx, int xs_full) {
  __shared__ __align__(16) char LA[2][16384];   // A tiles: 128 rows x 128B
  __shared__ __align__(16) char LB[2][16384];   // B tiles
  const int t = threadIdx.x;
  const int lane = t & 63, w = t >> 6;
  // bid pairs (2k,2k+1) share the A-panel and mix long(xrx)/short(xs) blocks.
  const int bid = blockIdx.x;
  const int half = bid & 1;                 // 0 -> xrx (long), 1 -> xs
  int e = bid >> 1;                          // 0..255
  e = (e & 7) * 32 + (e >> 3);               // XCD swizzle, bijective on 256
  const int bm = (e & 31) * 128;
  const int bn = (e >> 5) * 128 + (half ? 0 : 1024);
  const int wr = w >> 1, wc = w & 1;
  const bool full = (half == 0) || xs_full;

  f32x4 accM[4][4], accR[4][4];
#pragma unroll
  for (int m = 0; m < 4; ++m)
#pragma unroll
    for (int n = 0; n < 4; ++n) { accM[m][n] = (f32x4)0.f; accR[m][n] = (f32x4)0.f; }

  const int srow = lane >> 3;
  const int sin = (lane & 7) << 4;
  const int ar = wr * 64 + (lane & 15);
  const int br = wc * 64 + (lane & 15);
  const int kbyte = (lane >> 4) << 4;

  // prologue: stage piece-0 kt=0 into buf0
  stage_tiles(Xh, Wht, bm, bn, 0, w, srow, sin, LA[0], LB[0]);

  // piece 0: Xh@Wh -> accM, kts 0..15; last step prefetches piece 1 (if full)
#pragma unroll
  for (int kt = 0; kt < 16; ++kt) {
    const bool hn = (kt < 15) || full;
    const unsigned short* An = (kt < 15) ? Xh : Xh;
    const unsigned short* Bn = (kt < 15) ? Wht : Wlt;
    const int k0n = (kt < 15) ? (kt + 1) : 0;
    pipe_step(hn, An, Bn, k0n, kt & 1, bm, bn, w, srow, sin, ar, br, kbyte,
              LA, LB, accM);
  }
  if (full) {
    // piece 1: Xh@Wl_st -> accR, global kts 16..31 (parity continues: 16 even)
#pragma unroll
    for (int kt = 0; kt < 16; ++kt) {
      const unsigned short* An = (kt < 15) ? Xh : Xl;
      const unsigned short* Bn = (kt < 15) ? Wlt : Wht;
      const int k0n = (kt < 15) ? (kt + 1) : 0;
      pipe_step(true, An, Bn, k0n, kt & 1, bm, bn, w, srow, sin, ar, br, kbyte,
                LA, LB, accR);
    }
    // piece 2: Xl_st@Wh -> accR, global kts 32..47; last step no prefetch
#pragma unroll
    for (int kt = 0; kt < 16; ++kt) {
      pipe_step(kt < 15, Xl, Wht, kt + 1, kt & 1, bm, bn, w, srow, sin,
                ar, br, kbyte, LA, LB, accR);
    }
  }

  // epilogue: cols [0,1024) -> xs, [1024,2048) -> xrx (both [4096][1024])
  float* dst = (bn < 1024) ? xs : xrx;
  const int coff = bn & 1023;
  const int lrow = (lane >> 4) << 2;
  const int lcol = lane & 15;
#pragma unroll
  for (int m = 0; m < 4; ++m)
#pragma unroll
    for (int n = 0; n < 4; ++n) {
      const int gr = bm + wr * 64 + m * 16 + lrow;
      const int gc = coff + wc * 64 + n * 16 + lcol;
#pragma unroll
      for (int i = 0; i < 4; ++i)
        dst[((size_t)(gr + i) << 10) + gc] = accM[m][n][i] + accR[m][n][i] * RES_INV;
    }
}

// ------- out = tanh(xs + bself + A1[b]@xr_x[b] + A2[b]@xr_r + x_in) ----------
// Optionally also emits the fp16 split of out (for the next layer's GEMM).
__global__ __launch_bounds__(256) void k_agg(const float* __restrict__ A1,
                                             const float* __restrict__ A2,
                                             const float* __restrict__ xrx,
                                             const float* __restrict__ xrr,
                                             const float* __restrict__ xs,
                                             const float* __restrict__ bias,
                                             const float* __restrict__ xin,
                                             float* __restrict__ xout,
                                             unsigned short* __restrict__ XhO,
                                             unsigned short* __restrict__ XlO) {
  __shared__ float A1s[O][O + 1];
  __shared__ float A2s[O][RN + 1];
  __shared__ float Xls[O][132];
  __shared__ float Rls[RN][132];
  const int b = blockIdx.x;
  const int f0 = blockIdx.y * 128;
  const int t = threadIdx.x;

#pragma unroll
  for (int i = 0; i < 4; ++i) {
    const int gi = i * 1024 + t * 4;
    const float4 v = *reinterpret_cast<const float4*>(&A1[(size_t)b * O * O + gi]);
    const int o = gi >> 6, c = gi & 63;
    A1s[o][c] = v.x; A1s[o][c + 1] = v.y; A1s[o][c + 2] = v.z; A1s[o][c + 3] = v.w;
  }
  {
    const int gi = t * 4;
    const float4 v = *reinterpret_cast<const float4*>(&A2[(size_t)b * O * RN + gi]);
    const int o = gi >> 4, c = gi & 15;
    A2s[o][c] = v.x; A2s[o][c + 1] = v.y; A2s[o][c + 2] = v.z; A2s[o][c + 3] = v.w;
  }
#pragma unroll
  for (int i = 0; i < 8; ++i) {
    const int gi = i * 1024 + t * 4;
    const int o2 = gi >> 7, c = gi & 127;
    const float4 v = *reinterpret_cast<const float4*>(&xrx[((size_t)(b * O + o2)) * F + f0 + c]);
    Xls[o2][c] = v.x; Xls[o2][c + 1] = v.y; Xls[o2][c + 2] = v.z; Xls[o2][c + 3] = v.w;
  }
#pragma unroll
  for (int i = 0; i < 2; ++i) {
    const int gi = i * 1024 + t * 4;
    const int r = gi >> 7, c = gi & 127;
    const float4 v = *reinterpret_cast<const float4*>(&xrr[(size_t)r * F + f0 + c]);
    Rls[r][c] = v.x; Rls[r][c + 1] = v.y; Rls[r][c + 2] = v.z; Rls[r][c + 3] = v.w;
  }
  __syncthreads();

  const int ob = (t >> 4) << 2;
  const int fc = (t & 15) << 2;
  float acc[4][8];
#pragma unroll
  for (int i = 0; i < 4; ++i)
#pragma unroll
    for (int j = 0; j < 8; ++j) acc[i][j] = 0.f;

#pragma unroll 4
  for (int o2 = 0; o2 < O; ++o2) {
    const float4 xa = *reinterpret_cast<const float4*>(&Xls[o2][fc]);
    const float4 xb = *reinterpret_cast<const float4*>(&Xls[o2][fc + 64]);
#pragma unroll
    for (int io = 0; io < 4; ++io) {
      const float a = A1s[ob + io][o2];
      acc[io][0] += a * xa.x; acc[io][1] += a * xa.y; acc[io][2] += a * xa.z; acc[io][3] += a * xa.w;
      acc[io][4] += a * xb.x; acc[io][5] += a * xb.y; acc[io][6] += a * xb.z; acc[io][7] += a * xb.w;
    }
  }
#pragma unroll
  for (int r = 0; r < RN; ++r) {
    const float4 xa = *reinterpret_cast<const float4*>(&Rls[r][fc]);
    const float4 xb = *reinterpret_cast<const float4*>(&Rls[r][fc + 64]);
#pragma unroll
    for (int io = 0; io < 4; ++io) {
      const float a = A2s[ob + io][r];
      acc[io][0] += a * xa.x; acc[io][1] += a * xa.y; acc[io][2] += a * xa.z; acc[io][3] += a * xa.w;
      acc[io][4] += a * xb.x; acc[io][5] += a * xb.y; acc[io][6] += a * xb.z; acc[io][7] += a * xb.w;
    }
  }

#pragma unroll
  for (int io = 0; io < 4; ++io) {
    const size_t base = ((size_t)(b * O + ob + io)) * F + f0;
#pragma unroll
    for (int seg = 0; seg < 2; ++seg) {
      const size_t idx = base + seg * 64 + fc;
      const float4 s = *reinterpret_cast<const float4*>(&xs[idx]);
      const float4 bv = *reinterpret_cast<const float4*>(&bias[f0 + seg * 64 + fc]);
      const float4 xi = *reinterpret_cast<const float4*>(&xin[idx]);
      float4 o;
      o.x = tanhf(acc[io][seg * 4 + 0] + s.x + bv.x + xi.x);
      o.y = tanhf(acc[io][seg * 4 + 1] + s.y + bv.y + xi.y);
      o.z = tanhf(acc[io][seg * 4 + 2] + s.z + bv.z + xi.z);
      o.w = tanhf(acc[io][seg * 4 + 3] + s.w + bv.w + xi.w);
      *reinterpret_cast<float4*>(&xout[idx]) = o;
      if (XhO) {
        unsigned short h0, h1, h2, h3, l0, l1, l2, l3;
        split2(o.x, h0, l0); split2(o.y, h1, l1); split2(o.z, h2, l2); split2(o.w, h3, l3);
        uint2 hp, lp;
        hp.x = (unsigned)h0 | ((unsigned)h1 << 16); hp.y = (unsigned)h2 | ((unsigned)h3 << 16);
        lp.x = (unsigned)l0 | ((unsigned)l1 << 16); lp.y = (unsigned)l2 | ((unsigned)l3 << 16);
        *reinterpret_cast<uint2*>(&XhO[idx]) = hp;
        *reinterpret_cast<uint2*>(&XlO[idx]) = lp;
      }
    }
  }
}

extern "C" void kernel_launch(void* const* d_in, const int* in_sizes, int n_in,
                              void* d_out, int out_size, void* d_ws, size_t ws_size,
                              hipStream_t stream) {
  const float* x0    = (const float*)d_in[0];
  const float* A     = (const float*)d_in[1];
  const float* R     = (const float*)d_in[2];
  const float* Wself = (const float*)d_in[3];
  const float* bself = (const float*)d_in[4];
  const float* Wrel  = (const float*)d_in[5];
  const float* brel  = (const float*)d_in[6];
  float* out = (float*)d_out;

  float* ws  = (float*)d_ws;
  float* A1  = ws;                               // 1 MB
  float* A2  = A1 + (size_t)M * O;               // 0.25 MB
  float* xrr = A2 + (size_t)M * RN;              // 2 layers x RN x F
  float* xs  = xrr + (size_t)2 * RN * F;         // 16 MB
  float* xrx = xs + (size_t)M * F;               // 16 MB
  unsigned short* Xh  = (unsigned short*)(xrx + (size_t)M * F);    // 8 MB
  unsigned short* Xl  = Xh + (size_t)M * F;                        // 8 MB
  unsigned short* Wht = Xl + (size_t)M * F;      // 2 layers x [2048][1024] = 8 MB
  unsigned short* Wlt = Wht + (size_t)2 * 2048 * 1024;             // 8 MB
  // total ws use ~65 MB

  k_reduceA<<<M, 256, 0, stream>>>(A, A1, A2);
  k_splitX<<<4096, 256, 0, stream>>>(x0, Xh, Xl);
  k_splitW2<<<dim3(32, 32, 4), 256, 0, stream>>>(Wself, Wrel, Wht, Wlt);
  k_xrr<<<dim3(RN * 4, 2), 256, 0, stream>>>(R, Wrel, brel, xrr);

  for (int i = 0; i < DEPTH; ++i) {
    const float* X = (i == 0) ? x0 : out;
    const unsigned short* Wht_i = Wht + (size_t)i * 2048 * 1024;
    const unsigned short* Wlt_i = Wlt + (size_t)i * 2048 * 1024;
    const int xs_full = (i + 1 < DEPTH) ? 1 : 0;
    k_gemm_mfma<<<512, 256, 0, stream>>>(Xh, Xl, Wht_i, Wlt_i, xs, xrx, xs_full);
    const bool emit = (i + 1 < DEPTH);
    k_agg<<<dim3(B, F / 128), 256, 0, stream>>>(A1, A2, xrx,
                                                xrr + (size_t)i * RN * F, xs,
                                                bself + (size_t)i * F, X, out,
                                                emit ? Xh : nullptr,
                                                emit ? Xl : nullptr);
  }
}

// Round 11
// 183.307 us; speedup vs baseline: 1.3047x; 1.3047x over previous
//
#include <hip/hip_runtime.h>
#include <hip/hip_bf16.h>
#include <math.h>

#define B 64
#define O 64
#define F 1024
#define RN 16
#define RD 256
#define DEPTH 2
#define M (B*O)

typedef __attribute__((ext_vector_type(8))) _Float16 half8;
typedef __attribute__((ext_vector_type(4))) float f32x4;

#define RES_SCALE 2048.0f          // 2^11
#define RES_INV  (1.0f/2048.0f)

// ---------- fp16 split helpers: x = h + l*2^-11 (l stored pre-scaled) ----------
__device__ __forceinline__ unsigned short h2u(_Float16 h) {
  union { _Float16 h; unsigned short u; } c; c.h = h; return c.u;
}
__device__ __forceinline__ void split2(float x, unsigned short& h, unsigned short& l) {
  _Float16 hh = (_Float16)x;                       // RNE
  _Float16 ll = (_Float16)((x - (float)hh) * RES_SCALE);
  h = h2u(hh); l = h2u(ll);
}

__device__ __forceinline__ void gload_lds16(const unsigned short* g, void* l) {
  __builtin_amdgcn_global_load_lds(
      (const __attribute__((address_space(1))) unsigned int*)g,
      (__attribute__((address_space(3))) unsigned int*)l, 16, 0, 0);
}

// ---------------- A reductions: A1[b,o,o2] = sum_r A, A2[b,o,r] = sum_o2 A ----
__global__ __launch_bounds__(256) void k_reduceA(const float* __restrict__ A,
                                                 float* __restrict__ A1,
                                                 float* __restrict__ A2) {
  __shared__ float row[O * RN];
  const int bo = blockIdx.x;
  const int t = threadIdx.x;
  *reinterpret_cast<float4*>(&row[t * 4]) =
      *reinterpret_cast<const float4*>(&A[(size_t)bo * (O * RN) + t * 4]);
  __syncthreads();
  if (t < O) {
    float s = 0.f;
#pragma unroll
    for (int r = 0; r < RN; ++r) s += row[t * RN + r];
    A1[(size_t)bo * O + t] = s;
  } else if (t < O + RN) {
    const int r = t - O;
    float s = 0.f;
#pragma unroll
    for (int o2 = 0; o2 < O; ++o2) s += row[o2 * RN + r];
    A2[(size_t)bo * RN + r] = s;
  }
}

// ------- xr_r = R @ Wrel[i][F:] + brel[i] -> xrr[layer][RN][F], both layers ---
__global__ __launch_bounds__(256) void k_xrr(const float* __restrict__ R,
                                             const float* __restrict__ Wrel,
                                             const float* __restrict__ brel,
                                             float* __restrict__ xrr) {
  const int layer = blockIdx.y;
  const float* Wr = Wrel + (size_t)layer * (F + RD) * F + (size_t)F * F;
  const float* br = brel + (size_t)layer * F;
  const int r = blockIdx.x >> 2;
  const int n = ((blockIdx.x & 3) << 8) + threadIdx.x;
  float s = br[n];
  for (int k = 0; k < RD; ++k) s += R[r * RD + k] * Wr[(size_t)k * F + n];
  xrr[(size_t)layer * RN * F + (size_t)r * F + n] = s;
}

// ---------------- split X [4096][1024] f32 -> Xh, Xl fp16 (row-major) --------
__global__ __launch_bounds__(256) void k_splitX(const float* __restrict__ X,
                                                unsigned short* __restrict__ Xh,
                                                unsigned short* __restrict__ Xl) {
  const size_t i = ((size_t)blockIdx.x * 256 + threadIdx.x) * 4;
  const float4 v = *reinterpret_cast<const float4*>(&X[i]);
  unsigned short h0, h1, h2, h3, l0, l1, l2, l3;
  split2(v.x, h0, l0); split2(v.y, h1, l1); split2(v.z, h2, l2); split2(v.w, h3, l3);
  uint2 hp, lp;
  hp.x = (unsigned)h0 | ((unsigned)h1 << 16); hp.y = (unsigned)h2 | ((unsigned)h3 << 16);
  lp.x = (unsigned)l0 | ((unsigned)l1 << 16); lp.y = (unsigned)l2 | ((unsigned)l3 << 16);
  *reinterpret_cast<uint2*>(&Xh[i]) = hp;
  *reinterpret_cast<uint2*>(&Xl[i]) = lp;
}

// -- split + transpose W for BOTH layers upfront.
// z = layer*2 + sel; sel 0: Wself -> rows [0,1024); sel 1: Wrel[:F] -> rows [1024,2048).
__global__ __launch_bounds__(256) void k_splitW2(const float* __restrict__ Wself,
                                                 const float* __restrict__ Wrel,
                                                 unsigned short* __restrict__ Wht,
                                                 unsigned short* __restrict__ Wlt) {
  __shared__ float T[32][33];
  const int layer = blockIdx.z >> 1;
  const int sel = blockIdx.z & 1;
  const float* W = sel ? (Wrel + (size_t)layer * (F + RD) * F)
                       : (Wself + (size_t)layer * F * F);
  const size_t obase = (size_t)layer * 2048 * 1024 + (size_t)(sel ? 1024 : 0) * 1024;
  const int k0 = blockIdx.x * 32, n0 = blockIdx.y * 32;
  const int t = threadIdx.x;
  const int r = t >> 3, c4 = (t & 7) << 2;
  const float4 v = *reinterpret_cast<const float4*>(&W[(size_t)(k0 + r) * 1024 + n0 + c4]);
  T[r][c4] = v.x; T[r][c4 + 1] = v.y; T[r][c4 + 2] = v.z; T[r][c4 + 3] = v.w;
  __syncthreads();
  unsigned short h[4], l[4];
#pragma unroll
  for (int j = 0; j < 4; ++j) split2(T[c4 + j][r], h[j], l[j]);
  uint2 hp, lp;
  hp.x = (unsigned)h[0] | ((unsigned)h[1] << 16); hp.y = (unsigned)h[2] | ((unsigned)h[3] << 16);
  lp.x = (unsigned)l[0] | ((unsigned)l[1] << 16); lp.y = (unsigned)l[2] | ((unsigned)l[3] << 16);
  const size_t o = obase + (size_t)(n0 + r) * 1024 + k0 + c4;
  *reinterpret_cast<uint2*>(&Wht[o]) = hp;
  *reinterpret_cast<uint2*>(&Wlt[o]) = lp;
}

// ---------------- staging + compute helpers (8-wave block) -------------------
// 32 chunks of 1KB: c 0..15 -> A rows c*8..c*8+7, c 16..31 -> B rows (c-16)*8...
// Each wave stages 4 chunks; chunk source/dest are wave-uniform.
__device__ __forceinline__ void stage_tiles8(const unsigned short* __restrict__ Asrc,
                                             const unsigned short* __restrict__ Bsrc,
                                             int bm, int bn, int k0,
                                             int w, int lane,
                                             char* Al, char* Bl) {
  const int srow = lane >> 3;
  const int sin = (lane & 7) << 4;
#pragma unroll
  for (int i = 0; i < 4; ++i) {
    const int c = (w << 2) + i;          // 0..31, wave-uniform
    const int cc = c & 15;
    const int row = (cc << 3) + srow;
    const int inrow = sin ^ ((row & 7) << 4);   // pre-swizzled SOURCE byte
    const unsigned short* src = (c < 16) ? Asrc : Bsrc;
    const int rbase = (c < 16) ? bm : bn;
    char* ldst = (c < 16) ? Al : Bl;
    gload_lds16(src + ((size_t)(rbase + row) << 10) + k0 + (inrow >> 1), ldst + (cc << 10));
  }
}

// per-wave 64x32 output: 4 m-frags x 2 n-frags
__device__ __forceinline__ void compute_tile8(const char* Al, const char* Bl,
                                              int ar, int br, int kbyte,
                                              f32x4 (&acc)[4][2]) {
#pragma unroll
  for (int kk = 0; kk < 2; ++kk) {
    half8 a[4], b[2];
#pragma unroll
    for (int m = 0; m < 4; ++m) {
      const int row = ar + m * 16;
      const int off = (row << 7) + (((kk << 6) + kbyte) ^ ((row & 7) << 4));
      a[m] = *reinterpret_cast<const half8*>(&Al[off]);
    }
#pragma unroll
    for (int n = 0; n < 2; ++n) {
      const int row = br + n * 16;
      const int off = (row << 7) + (((kk << 6) + kbyte) ^ ((row & 7) << 4));
      b[n] = *reinterpret_cast<const half8*>(&Bl[off]);
    }
#pragma unroll
    for (int m = 0; m < 4; ++m)
#pragma unroll
      for (int n = 0; n < 2; ++n)
        acc[m][n] = __builtin_amdgcn_mfma_f32_16x16x32_f16(a[m], b[n], acc[m][n], 0, 0, 0);
  }
}

// 16-kt inner loop (K=1024), fixed sources, single accumulator, 2-barrier.
__device__ __forceinline__ void gemm_piece8(const unsigned short* __restrict__ Asrc,
                                            const unsigned short* __restrict__ Bsrc,
                                            int bm, int bn, int w, int lane,
                                            int ar, int br, int kbyte,
                                            char* Al, char* Bl, f32x4 (&acc)[4][2]) {
  for (int kt = 0; kt < 16; ++kt) {
    stage_tiles8(Asrc, Bsrc, bm, bn, kt << 6, w, lane, Al, Bl);
    __syncthreads();
    compute_tile8(Al, Bl, ar, br, kbyte, acc);
    __syncthreads();
  }
}

// ------- fused MFMA GEMM (R6 organization, 8 waves / 512 threads) -------------
// xrx half (bn>=1024): C = Xh@Wh + 2^-11*(Xh@Wl_st + Xl_st@Wh), K=3072 always.
// xs  half (bn< 1024): same if xs_full, else single product Xh@Wh (K=1024).
__global__ __launch_bounds__(512) void k_gemm_mfma(
    const unsigned short* __restrict__ Xh, const unsigned short* __restrict__ Xl,
    const unsigned short* __restrict__ Wht, const unsigned short* __restrict__ Wlt,
    float* __restrict__ xs, float* __restrict__ xrx, int xs_full) {
  __shared__ __align__(16) char Al[128 * 128];  // 128 rows x 128B (64 fp16 k)
  __shared__ __align__(16) char Bl[128 * 128];
  const int t = threadIdx.x;
  const int lane = t & 63, w = t >> 6;          // w 0..7
  // bid pairs (2k,2k+1) share the A-panel and mix long(xrx)/short(xs) blocks.
  const int bid = blockIdx.x;
  const int half = bid & 1;                 // 0 -> xrx (long), 1 -> xs
  int e = bid >> 1;                          // 0..255
  e = (e & 7) * 32 + (e >> 3);               // XCD swizzle, bijective on 256
  const int bm = (e & 31) * 128;
  const int bn = (e >> 5) * 128 + (half ? 0 : 1024);
  const int wr = w >> 2, wc = w & 3;         // wave tile: rows wr*64, cols wc*32
  const bool full = (half == 0) || xs_full;

  f32x4 accM[4][2], accR[4][2];
#pragma unroll
  for (int m = 0; m < 4; ++m)
#pragma unroll
    for (int n = 0; n < 2; ++n) { accM[m][n] = (f32x4)0.f; accR[m][n] = (f32x4)0.f; }

  const int ar = wr * 64 + (lane & 15);
  const int br = wc * 32 + (lane & 15);
  const int kbyte = (lane >> 4) << 4;

  // piece 0: Xh@Wh -> accM (K=1024)
  gemm_piece8(Xh, Wht, bm, bn, w, lane, ar, br, kbyte, Al, Bl, accM);
  // pieces 1,2: Xh@Wl_st, Xl_st@Wh -> accR (K=2048)
  if (full) {
    gemm_piece8(Xh, Wlt, bm, bn, w, lane, ar, br, kbyte, Al, Bl, accR);
    gemm_piece8(Xl, Wht, bm, bn, w, lane, ar, br, kbyte, Al, Bl, accR);
  }

  // epilogue: cols [0,1024) -> xs, [1024,2048) -> xrx (both [4096][1024])
  float* dst = (bn < 1024) ? xs : xrx;
  const int coff = bn & 1023;
  const int lrow = (lane >> 4) << 2;
  const int lcol = lane & 15;
#pragma unroll
  for (int m = 0; m < 4; ++m)
#pragma unroll
    for (int n = 0; n < 2; ++n) {
      const int gr = bm + wr * 64 + m * 16 + lrow;
      const int gc = coff + wc * 32 + n * 16 + lcol;
#pragma unroll
      for (int i = 0; i < 4; ++i)
        dst[((size_t)(gr + i) << 10) + gc] = accM[m][n][i] + accR[m][n][i] * RES_INV;
    }
}

// ------- out = tanh(xs + bself + A1[b]@xr_x[b] + A2[b]@xr_r + x_in) ----------
// Optionally also emits the fp16 split of out (for the next layer's GEMM).
__global__ __launch_bounds__(256) void k_agg(const float* __restrict__ A1,
                                             const float* __restrict__ A2,
                                             const float* __restrict__ xrx,
                                             const float* __restrict__ xrr,
                                             const float* __restrict__ xs,
                                             const float* __restrict__ bias,
                                             const float* __restrict__ xin,
                                             float* __restrict__ xout,
                                             unsigned short* __restrict__ XhO,
                                             unsigned short* __restrict__ XlO) {
  __shared__ float A1s[O][O + 1];
  __shared__ float A2s[O][RN + 1];
  __shared__ float Xls[O][132];
  __shared__ float Rls[RN][132];
  const int b = blockIdx.x;
  const int f0 = blockIdx.y * 128;
  const int t = threadIdx.x;

#pragma unroll
  for (int i = 0; i < 4; ++i) {
    const int gi = i * 1024 + t * 4;
    const float4 v = *reinterpret_cast<const float4*>(&A1[(size_t)b * O * O + gi]);
    const int o = gi >> 6, c = gi & 63;
    A1s[o][c] = v.x; A1s[o][c + 1] = v.y; A1s[o][c + 2] = v.z; A1s[o][c + 3] = v.w;
  }
  {
    const int gi = t * 4;
    const float4 v = *reinterpret_cast<const float4*>(&A2[(size_t)b * O * RN + gi]);
    const int o = gi >> 4, c = gi & 15;
    A2s[o][c] = v.x; A2s[o][c + 1] = v.y; A2s[o][c + 2] = v.z; A2s[o][c + 3] = v.w;
  }
#pragma unroll
  for (int i = 0; i < 8; ++i) {
    const int gi = i * 1024 + t * 4;
    const int o2 = gi >> 7, c = gi & 127;
    const float4 v = *reinterpret_cast<const float4*>(&xrx[((size_t)(b * O + o2)) * F + f0 + c]);
    Xls[o2][c] = v.x; Xls[o2][c + 1] = v.y; Xls[o2][c + 2] = v.z; Xls[o2][c + 3] = v.w;
  }
#pragma unroll
  for (int i = 0; i < 2; ++i) {
    const int gi = i * 1024 + t * 4;
    const int r = gi >> 7, c = gi & 127;
    const float4 v = *reinterpret_cast<const float4*>(&xrr[(size_t)r * F + f0 + c]);
    Rls[r][c] = v.x; Rls[r][c + 1] = v.y; Rls[r][c + 2] = v.z; Rls[r][c + 3] = v.w;
  }
  __syncthreads();

  const int ob = (t >> 4) << 2;
  const int fc = (t & 15) << 2;
  float acc[4][8];
#pragma unroll
  for (int i = 0; i < 4; ++i)
#pragma unroll
    for (int j = 0; j < 8; ++j) acc[i][j] = 0.f;

#pragma unroll 4
  for (int o2 = 0; o2 < O; ++o2) {
    const float4 xa = *reinterpret_cast<const float4*>(&Xls[o2][fc]);
    const float4 xb = *reinterpret_cast<const float4*>(&Xls[o2][fc + 64]);
#pragma unroll
    for (int io = 0; io < 4; ++io) {
      const float a = A1s[ob + io][o2];
      acc[io][0] += a * xa.x; acc[io][1] += a * xa.y; acc[io][2] += a * xa.z; acc[io][3] += a * xa.w;
      acc[io][4] += a * xb.x; acc[io][5] += a * xb.y; acc[io][6] += a * xb.z; acc[io][7] += a * xb.w;
    }
  }
#pragma unroll
  for (int r = 0; r < RN; ++r) {
    const float4 xa = *reinterpret_cast<const float4*>(&Rls[r][fc]);
    const float4 xb = *reinterpret_cast<const float4*>(&Rls[r][fc + 64]);
#pragma unroll
    for (int io = 0; io < 4; ++io) {
      const float a = A2s[ob + io][r];
      acc[io][0] += a * xa.x; acc[io][1] += a * xa.y; acc[io][2] += a * xa.z; acc[io][3] += a * xa.w;
      acc[io][4] += a * xb.x; acc[io][5] += a * xb.y; acc[io][6] += a * xb.z; acc[io][7] += a * xb.w;
    }
  }

#pragma unroll
  for (int io = 0; io < 4; ++io) {
    const size_t base = ((size_t)(b * O + ob + io)) * F + f0;
#pragma unroll
    for (int seg = 0; seg < 2; ++seg) {
      const size_t idx = base + seg * 64 + fc;
      const float4 s = *reinterpret_cast<const float4*>(&xs[idx]);
      const float4 bv = *reinterpret_cast<const float4*>(&bias[f0 + seg * 64 + fc]);
      const float4 xi = *reinterpret_cast<const float4*>(&xin[idx]);
      float4 o;
      o.x = tanhf(acc[io][seg * 4 + 0] + s.x + bv.x + xi.x);
      o.y = tanhf(acc[io][seg * 4 + 1] + s.y + bv.y + xi.y);
      o.z = tanhf(acc[io][seg * 4 + 2] + s.z + bv.z + xi.z);
      o.w = tanhf(acc[io][seg * 4 + 3] + s.w + bv.w + xi.w);
      *reinterpret_cast<float4*>(&xout[idx]) = o;
      if (XhO) {
        unsigned short h0, h1, h2, h3, l0, l1, l2, l3;
        split2(o.x, h0, l0); split2(o.y, h1, l1); split2(o.z, h2, l2); split2(o.w, h3, l3);
        uint2 hp, lp;
        hp.x = (unsigned)h0 | ((unsigned)h1 << 16); hp.y = (unsigned)h2 | ((unsigned)h3 << 16);
        lp.x = (unsigned)l0 | ((unsigned)l1 << 16); lp.y = (unsigned)l2 | ((unsigned)l3 << 16);
        *reinterpret_cast<uint2*>(&XhO[idx]) = hp;
        *reinterpret_cast<uint2*>(&XlO[idx]) = lp;
      }
    }
  }
}

extern "C" void kernel_launch(void* const* d_in, const int* in_sizes, int n_in,
                              void* d_out, int out_size, void* d_ws, size_t ws_size,
                              hipStream_t stream) {
  const float* x0    = (const float*)d_in[0];
  const float* A     = (const float*)d_in[1];
  const float* R     = (const float*)d_in[2];
  const float* Wself = (const float*)d_in[3];
  const float* bself = (const float*)d_in[4];
  const float* Wrel  = (const float*)d_in[5];
  const float* brel  = (const float*)d_in[6];
  float* out = (float*)d_out;

  float* ws  = (float*)d_ws;
  float* A1  = ws;                               // 1 MB
  float* A2  = A1 + (size_t)M * O;               // 0.25 MB
  float* xrr = A2 + (size_t)M * RN;              // 2 layers x RN x F
  float* xs  = xrr + (size_t)2 * RN * F;         // 16 MB
  float* xrx = xs + (size_t)M * F;               // 16 MB
  unsigned short* Xh  = (unsigned short*)(xrx + (size_t)M * F);    // 8 MB
  unsigned short* Xl  = Xh + (size_t)M * F;                        // 8 MB
  unsigned short* Wht = Xl + (size_t)M * F;      // 2 layers x [2048][1024] = 8 MB
  unsigned short* Wlt = Wht + (size_t)2 * 2048 * 1024;             // 8 MB
  // total ws use ~65 MB

  k_reduceA<<<M, 256, 0, stream>>>(A, A1, A2);
  k_splitX<<<4096, 256, 0, stream>>>(x0, Xh, Xl);
  k_splitW2<<<dim3(32, 32, 4), 256, 0, stream>>>(Wself, Wrel, Wht, Wlt);
  k_xrr<<<dim3(RN * 4, 2), 256, 0, stream>>>(R, Wrel, brel, xrr);

  for (int i = 0; i < DEPTH; ++i) {
    const float* X = (i == 0) ? x0 : out;
    const unsigned short* Wht_i = Wht + (size_t)i * 2048 * 1024;
    const unsigned short* Wlt_i = Wlt + (size_t)i * 2048 * 1024;
    const int xs_full = (i + 1 < DEPTH) ? 1 : 0;
    k_gemm_mfma<<<512, 512, 0, stream>>>(Xh, Xl, Wht_i, Wlt_i, xs, xrx, xs_full);
    const bool emit = (i + 1 < DEPTH);
    k_agg<<<dim3(B, F / 128), 256, 0, stream>>>(A1, A2, xrx,
                                                xrr + (size_t)i * RN * F, xs,
                                                bself + (size_t)i * F, X, out,
                                                emit ? Xh : nullptr,
                                                emit ? Xl : nullptr);
  }
}